// Round 4
// baseline (7486.963 us; speedup 1.0000x reference)
//
#include <hip/hip_runtime.h>

#define TS 3584
#define VS 1792
#define TPF 448
#define NHEAD 12
#define HDIM 128
#define DMODEL 1536
#define ATTN_SCALE 0.08838834764831845f

typedef unsigned short u16;
typedef unsigned int u32;

__device__ __forceinline__ float u2f(u32 u) { union { u32 u; float f; } c; c.u = u; return c.f; }
__device__ __forceinline__ float blo(u32 u) { return u2f(u << 16); }
__device__ __forceinline__ float bhi(u32 u) { return u2f(u & 0xffff0000u); }
__device__ __forceinline__ u16 f2b(float f) {
  union { float f; u32 u; } c; c.f = f;
  return (u16)((c.u + 0x7fffu + ((c.u >> 16) & 1u)) >> 16);
}

__device__ __forceinline__ void load8(const float* p, float* d) {
  float4 a = *(const float4*)p, b = *(const float4*)(p + 4);
  d[0] = a.x; d[1] = a.y; d[2] = a.z; d[3] = a.w;
  d[4] = b.x; d[5] = b.y; d[6] = b.z; d[7] = b.w;
}
__device__ __forceinline__ void load8(const u16* p, float* d) {
  uint4 a = *(const uint4*)p;
  d[0] = blo(a.x); d[1] = bhi(a.x); d[2] = blo(a.y); d[3] = bhi(a.y);
  d[4] = blo(a.z); d[5] = bhi(a.z); d[6] = blo(a.w); d[7] = bhi(a.w);
}

// C[m,n] = sum_k A[m,k] * W[n,k] + bias[n]. 128x128 tile, 256 thr, 8x8 micro-tile.
// OUT_F32: write fp32 (the harness d_out is fp32 — reference output dtype is float32).
// Otherwise: write packed bf16 (internal intermediates).
template <typename TA, bool OUT_F32>
__device__ __forceinline__ void gemm_nt_body(const TA* A, const float* W,
                                             const float* bias, void* Cv,
                                             int M, int N, int K, int bx, int by) {
  __shared__ float As[16][128];
  __shared__ float Bs[16][128];
  const int tid = threadIdx.x;
  const int m0 = by * 128, n0 = bx * 128;
  const int lrow = tid >> 1;
  const int lk = (tid & 1) << 3;
  const int tx = tid & 15, ty = tid >> 4;
  float acc[8][8] = {};
  const TA* Ap = A + (size_t)(m0 + lrow) * K + lk;
  const float* Wp = W + (size_t)(n0 + lrow) * K + lk;
  for (int k0 = 0; k0 < K; k0 += 16) {
    float av[8], bv[8];
    load8(Ap + k0, av);
    load8(Wp + k0, bv);
    __syncthreads();
#pragma unroll
    for (int j = 0; j < 8; ++j) { As[lk + j][lrow] = av[j]; Bs[lk + j][lrow] = bv[j]; }
    __syncthreads();
#pragma unroll
    for (int kk = 0; kk < 16; ++kk) {
      float a[8], b[8];
      *(float4*)&a[0] = *(const float4*)&As[kk][ty * 8];
      *(float4*)&a[4] = *(const float4*)&As[kk][ty * 8 + 4];
      *(float4*)&b[0] = *(const float4*)&Bs[kk][tx * 8];
      *(float4*)&b[4] = *(const float4*)&Bs[kk][tx * 8 + 4];
#pragma unroll
      for (int i = 0; i < 8; ++i)
#pragma unroll
        for (int j = 0; j < 8; ++j) acc[i][j] = fmaf(a[i], b[j], acc[i][j]);
    }
  }
  float bvs[8];
#pragma unroll
  for (int j = 0; j < 8; ++j) bvs[j] = bias[n0 + tx * 8 + j];
#pragma unroll
  for (int i = 0; i < 8; ++i) {
    const int row = m0 + ty * 8 + i;
    if constexpr (OUT_F32) {
      float* C = (float*)Cv;
      float4 f0 = make_float4(acc[i][0] + bvs[0], acc[i][1] + bvs[1],
                              acc[i][2] + bvs[2], acc[i][3] + bvs[3]);
      float4 f1 = make_float4(acc[i][4] + bvs[4], acc[i][5] + bvs[5],
                              acc[i][6] + bvs[6], acc[i][7] + bvs[7]);
      *(float4*)(C + (size_t)row * N + n0 + tx * 8) = f0;
      *(float4*)(C + (size_t)row * N + n0 + tx * 8 + 4) = f1;
    } else {
      u16* C = (u16*)Cv;
      u32 pk[4];
#pragma unroll
      for (int jj = 0; jj < 4; ++jj) {
        u32 lo = f2b(acc[i][2 * jj] + bvs[2 * jj]);
        u32 hi = f2b(acc[i][2 * jj + 1] + bvs[2 * jj + 1]);
        pk[jj] = lo | (hi << 16);
      }
      *(uint4*)(C + (size_t)row * N + n0 + tx * 8) = make_uint4(pk[0], pk[1], pk[2], pk[3]);
    }
  }
}

__global__ __launch_bounds__(256) void gemm_qkv(
    const float* __restrict__ x,
    const float* __restrict__ qw, const float* __restrict__ qb,
    const float* __restrict__ kw, const float* __restrict__ kb,
    const float* __restrict__ vw, const float* __restrict__ vb,
    u16* __restrict__ qo, u16* __restrict__ ko, u16* __restrict__ vo) {
  const float* W = blockIdx.z == 0 ? qw : (blockIdx.z == 1 ? kw : vw);
  const float* B = blockIdx.z == 0 ? qb : (blockIdx.z == 1 ? kb : vb);
  u16* O = blockIdx.z == 0 ? qo : (blockIdx.z == 1 ? ko : vo);
  gemm_nt_body<float, false>(x, W, B, O, TS, DMODEL, DMODEL, blockIdx.x, blockIdx.y);
}

__global__ __launch_bounds__(256) void gemm_out(
    const u16* __restrict__ A, const float* __restrict__ W,
    const float* __restrict__ B, float* __restrict__ C) {
  gemm_nt_body<u16, true>(A, W, B, C, TS, DMODEL, DMODEL, blockIdx.x, blockIdx.y);
}

// In-place RMSNorm(+weight) then RoPE on bf16 rows. blockIdx.x = token; y: 0=q,1=k.
__global__ __launch_bounds__(256) void rmsnorm_rope(
    u16* qbuf, u16* kbuf, const float* __restrict__ freqs,
    const float* __restrict__ nqw, const float* __restrict__ nkw) {
  const int tok = blockIdx.x;
  u32* row = (u32*)((blockIdx.y == 0 ? qbuf : kbuf) + (size_t)tok * DMODEL);  // 768 pairs
  const float* w = blockIdx.y == 0 ? nqw : nkw;
  const int t = threadIdx.x;
  const u32 u0 = row[t], u1 = row[t + 256], u2 = row[t + 512];
  float px[3] = { blo(u0), blo(u1), blo(u2) };
  float py[3] = { bhi(u0), bhi(u1), bhi(u2) };
  float ss = px[0] * px[0] + py[0] * py[0] + px[1] * px[1] + py[1] * py[1] +
             px[2] * px[2] + py[2] * py[2];
#pragma unroll
  for (int off = 32; off; off >>= 1) ss += __shfl_xor(ss, off);
  __shared__ float red[4];
  if ((t & 63) == 0) red[t >> 6] = ss;
  __syncthreads();
  const float rstd = rsqrtf((red[0] + red[1] + red[2] + red[3]) * (1.0f / DMODEL) + 1e-6f);
  const int p = tok % VS;
  const int fi = p / TPF, rem = p % TPF, hi = rem / 28, wi = rem % 28;
#pragma unroll
  for (int jj = 0; jj < 3; ++jj) {
    const int pj = t + jj * 256;               // pair index over DMODEL/2=768
    const int i = pj & 63;                     // pair index within head (HD/2=64)
    const int prow = (i < 22) ? fi : ((i < 43) ? hi : wi);
    const float ang = freqs[prow * 64 + i];
    float sn, cs;
    sincosf(ang, &sn, &cs);
    const float a = px[jj] * rstd * w[2 * pj], b = py[jj] * rstd * w[2 * pj + 1];
    row[pj] = (u32)f2b(a * cs - b * sn) | ((u32)f2b(a * sn + b * cs) << 16);
  }
}

// Fused union-softmax attention (in-view 1792 keys + cross-view same-frame 448 keys).
// Equals the reference's logaddexp combine of (attn_i, attn_c): disjoint key sets.
// 4 waves/block, 4 queries/wave; 32x128 bf16 K/V tiles in LDS. fused may alias q.
__global__ __launch_bounds__(256) void attn_fused(
    const u16* q, const u16* __restrict__ k, const u16* __restrict__ v, u16* fused) {
  __shared__ u16 Ks[32][HDIM];
  __shared__ u16 Vs[32][HDIM];
  const int h = blockIdx.y;
  const int wave = threadIdx.x >> 6;
  const int lane = threadIdx.x & 63;
  const int tok0 = blockIdx.x * 16 + wave * 4;   // 16 tokens/block share (view, frame)
  const int vview = tok0 / VS;
  const int fidx = (tok0 % VS) / TPF;

  float qx[4], qy[4], mm[4], ls[4], a0[4], a1[4];
#pragma unroll
  for (int qi = 0; qi < 4; ++qi) {
    const u32 uq = ((const u32*)(q + (size_t)(tok0 + qi) * DMODEL + h * HDIM))[lane];
    qx[qi] = blo(uq); qy[qi] = bhi(uq);
    mm[qi] = -1e30f; ls[qi] = 0.f; a0[qi] = 0.f; a1[qi] = 0.f;
  }

  const int base0 = vview * VS;
  const int base1 = (1 - vview) * VS + fidx * TPF;
  for (int r = 0; r < 2; ++r) {
    const int base = (r == 0) ? base0 : base1;
    const int cnt = (r == 0) ? VS : TPF;
    for (int t0 = 0; t0 < cnt; t0 += 32) {
      __syncthreads();
#pragma unroll
      for (int j = 0; j < 2; ++j) {
        const int idx = threadIdx.x + j * 256;   // 512 x 16B chunks per tensor
        const int key = idx >> 4;
        const int off = (idx & 15) << 3;
        const size_t g = (size_t)(base + t0 + key) * DMODEL + h * HDIM + off;
        *(uint4*)&Ks[key][off] = *(const uint4*)(k + g);
        *(uint4*)&Vs[key][off] = *(const uint4*)(v + g);
      }
      __syncthreads();
#pragma unroll 4
      for (int j = 0; j < 32; ++j) {
        const u32 ku = ((const u32*)Ks[j])[lane];
        const u32 vu = ((const u32*)Vs[j])[lane];
        const float kx = blo(ku), ky = bhi(ku);
        const float vx = blo(vu), vy = bhi(vu);
        float part[4];
#pragma unroll
        for (int qi = 0; qi < 4; ++qi) part[qi] = qx[qi] * kx + qy[qi] * ky;
#pragma unroll
        for (int off = 32; off; off >>= 1) {
#pragma unroll
          for (int qi = 0; qi < 4; ++qi) part[qi] += __shfl_xor(part[qi], off);
        }
#pragma unroll
        for (int qi = 0; qi < 4; ++qi) {
          const float logit = part[qi] * ATTN_SCALE;
          if (logit <= mm[qi]) {                  // wave-uniform branch
            const float pr = __expf(logit - mm[qi]);
            a0[qi] = fmaf(pr, vx, a0[qi]);
            a1[qi] = fmaf(pr, vy, a1[qi]);
            ls[qi] += pr;
          } else {
            const float c = __expf(mm[qi] - logit);
            a0[qi] = fmaf(a0[qi], c, vx);
            a1[qi] = fmaf(a1[qi], c, vy);
            ls[qi] = fmaf(ls[qi], c, 1.0f);
            mm[qi] = logit;
          }
        }
      }
    }
  }
#pragma unroll
  for (int qi = 0; qi < 4; ++qi) {
    const float inv = 1.0f / ls[qi];
    u32* dst = (u32*)(fused + (size_t)(tok0 + qi) * DMODEL + h * HDIM);
    dst[lane] = (u32)f2b(a0[qi] * inv) | ((u32)f2b(a1[qi] * inv) << 16);
  }
}

extern "C" void kernel_launch(void* const* d_in, const int* in_sizes, int n_in,
                              void* d_out, int out_size, void* d_ws, size_t ws_size,
                              hipStream_t stream) {
  (void)in_sizes; (void)n_in; (void)out_size; (void)ws_size;
  const float* x   = (const float*)d_in[0];
  const float* fr  = (const float*)d_in[1];
  const float* qw  = (const float*)d_in[2];
  const float* qb  = (const float*)d_in[3];
  const float* kw  = (const float*)d_in[4];
  const float* kb  = (const float*)d_in[5];
  const float* vw  = (const float*)d_in[6];
  const float* vb  = (const float*)d_in[7];
  const float* ow  = (const float*)d_in[8];
  const float* ob  = (const float*)d_in[9];
  const float* nqw = (const float*)d_in[10];
  const float* nkw = (const float*)d_in[11];

  // Intermediates (bf16): q (later fused) + v in ws (22 MB); k borrows the first
  // 11 MB of d_out (fp32 22 MB) — k is dead before gemm_out overwrites d_out.
  u16* qf = (u16*)d_ws;
  u16* vf = qf + (size_t)TS * DMODEL;
  u16* kf = (u16*)d_out;

  gemm_qkv<<<dim3(DMODEL / 128, TS / 128, 3), dim3(256), 0, stream>>>(
      x, qw, qb, kw, kb, vw, vb, qf, kf, vf);
  rmsnorm_rope<<<dim3(TS, 2), dim3(256), 0, stream>>>(qf, kf, fr, nqw, nkw);
  attn_fused<<<dim3(TS / 16, NHEAD), dim3(256), 0, stream>>>(qf, kf, vf, qf);
  gemm_out<<<dim3(DMODEL / 128, TS / 128), dim3(256), 0, stream>>>(
      qf, ow, ob, (float*)d_out);
}

// Round 6
// 1143.369 us; speedup vs baseline: 6.5482x; 6.5482x over previous
//
#include <hip/hip_runtime.h>

#define TS 3584
#define VS 1792
#define TPF 448
#define NHEAD 12
#define HDIM 128
#define DMODEL 1536
#define ATTN_SCALE 0.08838834764831845f

typedef unsigned short u16;
typedef unsigned int u32;
typedef __attribute__((ext_vector_type(8))) short bf16x8;
typedef __attribute__((ext_vector_type(4))) float f32x4;

__device__ __forceinline__ float u2f(u32 u) { union { u32 u; float f; } c; c.u = u; return c.f; }
__device__ __forceinline__ float blo(u32 u) { return u2f(u << 16); }
__device__ __forceinline__ float bhi(u32 u) { return u2f(u & 0xffff0000u); }
__device__ __forceinline__ u16 f2b(float f) {
  union { float f; u32 u; } c; c.f = f;
  return (u16)((c.u + 0x7fffu + ((c.u >> 16) & 1u)) >> 16);
}

__device__ __forceinline__ void load8(const float* p, float* d) {
  float4 a = *(const float4*)p, b = *(const float4*)(p + 4);
  d[0] = a.x; d[1] = a.y; d[2] = a.z; d[3] = a.w;
  d[4] = b.x; d[5] = b.y; d[6] = b.z; d[7] = b.w;
}
__device__ __forceinline__ void load8(const u16* p, float* d) {
  uint4 a = *(const uint4*)p;
  d[0] = blo(a.x); d[1] = bhi(a.x); d[2] = blo(a.y); d[3] = bhi(a.y);
  d[4] = blo(a.z); d[5] = bhi(a.z); d[6] = blo(a.w); d[7] = bhi(a.w);
}

// C[m,n] = sum_k A[m,k] * W[n,k] + bias[n]. 128x128 tile, 256 thr, 8x8 micro-tile.
template <typename TA, bool OUT_F32>
__device__ __forceinline__ void gemm_nt_body(const TA* A, const float* W,
                                             const float* bias, void* Cv,
                                             int M, int N, int K, int bx, int by) {
  __shared__ float As[16][128];
  __shared__ float Bs[16][128];
  const int tid = threadIdx.x;
  const int m0 = by * 128, n0 = bx * 128;
  const int lrow = tid >> 1;
  const int lk = (tid & 1) << 3;
  const int tx = tid & 15, ty = tid >> 4;
  float acc[8][8] = {};
  const TA* Ap = A + (size_t)(m0 + lrow) * K + lk;
  const float* Wp = W + (size_t)(n0 + lrow) * K + lk;
  for (int k0 = 0; k0 < K; k0 += 16) {
    float av[8], bv[8];
    load8(Ap + k0, av);
    load8(Wp + k0, bv);
    __syncthreads();
#pragma unroll
    for (int j = 0; j < 8; ++j) { As[lk + j][lrow] = av[j]; Bs[lk + j][lrow] = bv[j]; }
    __syncthreads();
#pragma unroll
    for (int kk = 0; kk < 16; ++kk) {
      float a[8], b[8];
      *(float4*)&a[0] = *(const float4*)&As[kk][ty * 8];
      *(float4*)&a[4] = *(const float4*)&As[kk][ty * 8 + 4];
      *(float4*)&b[0] = *(const float4*)&Bs[kk][tx * 8];
      *(float4*)&b[4] = *(const float4*)&Bs[kk][tx * 8 + 4];
#pragma unroll
      for (int i = 0; i < 8; ++i)
#pragma unroll
        for (int j = 0; j < 8; ++j) acc[i][j] = fmaf(a[i], b[j], acc[i][j]);
    }
  }
  float bvs[8];
#pragma unroll
  for (int j = 0; j < 8; ++j) bvs[j] = bias[n0 + tx * 8 + j];
#pragma unroll
  for (int i = 0; i < 8; ++i) {
    const int row = m0 + ty * 8 + i;
    if constexpr (OUT_F32) {
      float* C = (float*)Cv;
      float4 f0 = make_float4(acc[i][0] + bvs[0], acc[i][1] + bvs[1],
                              acc[i][2] + bvs[2], acc[i][3] + bvs[3]);
      float4 f1 = make_float4(acc[i][4] + bvs[4], acc[i][5] + bvs[5],
                              acc[i][6] + bvs[6], acc[i][7] + bvs[7]);
      *(float4*)(C + (size_t)row * N + n0 + tx * 8) = f0;
      *(float4*)(C + (size_t)row * N + n0 + tx * 8 + 4) = f1;
    } else {
      u16* C = (u16*)Cv;
      u32 pk[4];
#pragma unroll
      for (int jj = 0; jj < 4; ++jj) {
        u32 lo = f2b(acc[i][2 * jj] + bvs[2 * jj]);
        u32 hi = f2b(acc[i][2 * jj + 1] + bvs[2 * jj + 1]);
        pk[jj] = lo | (hi << 16);
      }
      *(uint4*)(C + (size_t)row * N + n0 + tx * 8) = make_uint4(pk[0], pk[1], pk[2], pk[3]);
    }
  }
}

__global__ __launch_bounds__(256) void gemm_qkv(
    const float* __restrict__ x,
    const float* __restrict__ qw, const float* __restrict__ qb,
    const float* __restrict__ kw, const float* __restrict__ kb,
    const float* __restrict__ vw, const float* __restrict__ vb,
    u16* __restrict__ qo, u16* __restrict__ ko, u16* __restrict__ vo) {
  const float* W = blockIdx.z == 0 ? qw : (blockIdx.z == 1 ? kw : vw);
  const float* B = blockIdx.z == 0 ? qb : (blockIdx.z == 1 ? kb : vb);
  u16* O = blockIdx.z == 0 ? qo : (blockIdx.z == 1 ? ko : vo);
  gemm_nt_body<float, false>(x, W, B, O, TS, DMODEL, DMODEL, blockIdx.x, blockIdx.y);
}

__global__ __launch_bounds__(256) void gemm_out(
    const u16* __restrict__ A, const float* __restrict__ W,
    const float* __restrict__ B, float* __restrict__ C) {
  gemm_nt_body<u16, true>(A, W, B, C, TS, DMODEL, DMODEL, blockIdx.x, blockIdx.y);
}

// In-place RMSNorm(+weight) then RoPE on bf16 rows. blockIdx.x = token; y: 0=q,1=k.
__global__ __launch_bounds__(256) void rmsnorm_rope(
    u16* qbuf, u16* kbuf, const float* __restrict__ freqs,
    const float* __restrict__ nqw, const float* __restrict__ nkw) {
  const int tok = blockIdx.x;
  u32* row = (u32*)((blockIdx.y == 0 ? qbuf : kbuf) + (size_t)tok * DMODEL);
  const float* w = blockIdx.y == 0 ? nqw : nkw;
  const int t = threadIdx.x;
  const u32 u0 = row[t], u1 = row[t + 256], u2 = row[t + 512];
  float px[3] = { blo(u0), blo(u1), blo(u2) };
  float py[3] = { bhi(u0), bhi(u1), bhi(u2) };
  float ss = px[0] * px[0] + py[0] * py[0] + px[1] * px[1] + py[1] * py[1] +
             px[2] * px[2] + py[2] * py[2];
#pragma unroll
  for (int off = 32; off; off >>= 1) ss += __shfl_xor(ss, off);
  __shared__ float red[4];
  if ((t & 63) == 0) red[t >> 6] = ss;
  __syncthreads();
  const float rstd = rsqrtf((red[0] + red[1] + red[2] + red[3]) * (1.0f / DMODEL) + 1e-6f);
  const int p = tok % VS;
  const int fi = p / TPF, rem = p % TPF, hi = rem / 28, wi = rem % 28;
#pragma unroll
  for (int jj = 0; jj < 3; ++jj) {
    const int pj = t + jj * 256;
    const int i = pj & 63;
    const int prow = (i < 22) ? fi : ((i < 43) ? hi : wi);
    const float ang = freqs[prow * 64 + i];
    float sn, cs;
    sincosf(ang, &sn, &cs);
    const float a = px[jj] * rstd * w[2 * pj], b = py[jj] * rstd * w[2 * pj + 1];
    row[pj] = (u32)f2b(a * cs - b * sn) | ((u32)f2b(a * sn + b * cs) << 16);
  }
}

// vt[h][hd][tok] = v[tok][h*128+hd]. 128-thread blocks; in-register 8x8 u16 transpose.
// Each thread transposes TWO 8x8 tiles (128 tok x 128 hd total per block).
__global__ __launch_bounds__(128) void transpose_v(
    const u16* __restrict__ v, u16* __restrict__ vt) {
  __shared__ __align__(16) u16 T[128 * 128];
  const int h = blockIdx.y;
  const int t0 = blockIdx.x * 128;
  const int t = threadIdx.x;
#pragma unroll
  for (int i = 0; i < 16; ++i) {
    int idx = t + i * 128;
    int tok = idx >> 4, hd8 = idx & 15;
    *(uint4*)&T[tok * 128 + ((hd8 ^ (tok & 7)) * 8)] =
        *(const uint4*)(v + (size_t)(t0 + tok) * DMODEL + h * HDIM + hd8 * 8);
  }
  __syncthreads();
  const int hb = t >> 3;                       // 16 hd-blocks
#pragma unroll
  for (int half = 0; half < 2; ++half) {
    const int tb = (t & 7) + half * 8;         // 16 tok-blocks (was 8: the r5 bug)
    uint4 M[8];
#pragma unroll
    for (int r = 0; r < 8; ++r)
      M[r] = *(const uint4*)&T[(tb * 8 + r) * 128 + ((hb ^ r) * 8)];  // tok&7 == r
    uint4 O[8];
#pragma unroll
    for (int c2 = 0; c2 < 4; ++c2) {
      const u32* A = (const u32*)&M[2 * c2];
      const u32* Bp = (const u32*)&M[2 * c2 + 1];
#pragma unroll
      for (int jh = 0; jh < 4; ++jh) {
        u32 a = A[jh], b = Bp[jh];
        ((u32*)&O[2 * jh])[c2] = (a & 0xffffu) | (b << 16);
        ((u32*)&O[2 * jh + 1])[c2] = (a >> 16) | (b & 0xffff0000u);
      }
    }
#pragma unroll
    for (int j = 0; j < 8; ++j)
      *(uint4*)(vt + (size_t)(h * HDIM + hb * 8 + j) * TS + t0 + tb * 8) = O[j];
  }
}

// MFMA flash attention over union key set (in-view 1792 + cross-view same-frame 448).
// Block = 64 queries (one frame) x 1 head; 4 waves x 16 queries.
// S^T = K*Q^T (C-layout col=query) -> online softmax lane-local per query ->
// P via LDS round-trip to B-operand layout -> O^T = Vt*P (col=query again).
// All LDS tiles XOR-swizzled for conflict-free aligned ds_read_b128.
__global__ __launch_bounds__(256) void attn_mfma(
    const u16* q, const u16* __restrict__ k,
    const u16* __restrict__ vt, u16* fused) {
  __shared__ __align__(16) u16 Kls[32 * 128];
  __shared__ __align__(16) u16 Vls[128 * 32];
  __shared__ __align__(16) u16 Qls[64 * 128];
  __shared__ __align__(16) u16 Pls[4][16 * 48];
  const int h = blockIdx.y;
  const int q0 = blockIdx.x * 64;
  const int t = threadIdx.x;
  const int wave = t >> 6;
  const int lane = t & 63;
  const int col = lane & 15, quad = lane >> 4;
  const int vview = q0 / VS;
  const int fidx = (q0 % VS) / TPF;

  // Stage Q (64 x 128), swizzled chunks
#pragma unroll
  for (int i = 0; i < 4; ++i) {
    int idx = t + i * 256;
    int qr = idx >> 4, hd8 = idx & 15;
    *(uint4*)&Qls[qr * 128 + ((hd8 ^ (qr & 7)) * 8)] =
        *(const uint4*)(q + (size_t)(q0 + qr) * DMODEL + h * HDIM + hd8 * 8);
  }
  __syncthreads();
  bf16x8 qfrag[4];
#pragma unroll
  for (int c = 0; c < 4; ++c)
    qfrag[c] = *(const bf16x8*)&Qls[(wave * 16 + col) * 128 +
                                    (((c * 4 + quad) ^ (col & 7)) * 8)];

  f32x4 accO[8];
#pragma unroll
  for (int c = 0; c < 8; ++c) accO[c] = (f32x4){0.f, 0.f, 0.f, 0.f};
  float m_run = -1e30f, l_run = 0.f;

  const int base0 = vview * VS;
  const int base1 = (1 - vview) * VS + fidx * TPF;

  for (int it = 0; it < 70; ++it) {
    const int base = (it < 56) ? (base0 + it * 32) : (base1 + (it - 56) * 32);
    __syncthreads();
#pragma unroll
    for (int i = 0; i < 2; ++i) {
      int idx = t + i * 256;
      int key = idx >> 4, hd8 = idx & 15;
      *(uint4*)&Kls[key * 128 + ((hd8 ^ (key & 7)) * 8)] =
          *(const uint4*)(k + (size_t)(base + key) * DMODEL + h * HDIM + hd8 * 8);
      int hd = idx >> 2, t8 = idx & 3;
      *(uint4*)&Vls[hd * 32 + ((t8 ^ (hd & 3)) * 8)] =
          *(const uint4*)(vt + (size_t)(h * HDIM + hd) * TS + base + t8 * 8);
    }
    __syncthreads();

    // QK^T: S^T [32 keys x 16 q], rows=keys
    f32x4 s0 = (f32x4){0.f, 0.f, 0.f, 0.f}, s1 = (f32x4){0.f, 0.f, 0.f, 0.f};
#pragma unroll
    for (int c = 0; c < 4; ++c) {
      const int chn = ((c * 4 + quad) ^ (col & 7)) * 8;
      bf16x8 ka0 = *(const bf16x8*)&Kls[col * 128 + chn];
      bf16x8 ka1 = *(const bf16x8*)&Kls[(16 + col) * 128 + chn];
      s0 = __builtin_amdgcn_mfma_f32_16x16x32_bf16(ka0, qfrag[c], s0, 0, 0, 0);
      s1 = __builtin_amdgcn_mfma_f32_16x16x32_bf16(ka1, qfrag[c], s1, 0, 0, 0);
    }

    // online softmax; per-query state lane-local (col = query)
    float lmax = -1e30f;
#pragma unroll
    for (int r = 0; r < 4; ++r) {
      s0[r] *= ATTN_SCALE; s1[r] *= ATTN_SCALE;
      lmax = fmaxf(lmax, fmaxf(s0[r], s1[r]));
    }
    lmax = fmaxf(lmax, __shfl_xor(lmax, 16));
    lmax = fmaxf(lmax, __shfl_xor(lmax, 32));
    const float mnew = fmaxf(m_run, lmax);
    const float alpha = __expf(m_run - mnew);
    float p0[4], p1[4], ps = 0.f;
#pragma unroll
    for (int r = 0; r < 4; ++r) {
      p0[r] = __expf(s0[r] - mnew);
      p1[r] = __expf(s1[r] - mnew);
      ps += p0[r] + p1[r];
    }
    ps += __shfl_xor(ps, 16);
    ps += __shfl_xor(ps, 32);
    l_run = l_run * alpha + ps;
    m_run = mnew;
#pragma unroll
    for (int c = 0; c < 8; ++c) {
      accO[c][0] *= alpha; accO[c][1] *= alpha;
      accO[c][2] *= alpha; accO[c][3] *= alpha;
    }

    // P^T (C-layout) -> LDS as P[q][key] (B-operand order), wave-private
    uint2 w0, w1;
    w0.x = (u32)f2b(p0[0]) | ((u32)f2b(p0[1]) << 16);
    w0.y = (u32)f2b(p0[2]) | ((u32)f2b(p0[3]) << 16);
    w1.x = (u32)f2b(p1[0]) | ((u32)f2b(p1[1]) << 16);
    w1.y = (u32)f2b(p1[2]) | ((u32)f2b(p1[3]) << 16);
    *(uint2*)&Pls[wave][col * 48 + quad * 4] = w0;
    *(uint2*)&Pls[wave][col * 48 + 16 + quad * 4] = w1;
    asm volatile("s_waitcnt lgkmcnt(0)" ::: "memory");
    bf16x8 pf = *(const bf16x8*)&Pls[wave][col * 48 + quad * 8];

    // O^T += Vt * P : 8 hd-chunks, col=query
#pragma unroll
    for (int c = 0; c < 8; ++c) {
      bf16x8 va = *(const bf16x8*)&Vls[(c * 16 + col) * 32 + ((quad ^ (col & 3)) * 8)];
      accO[c] = __builtin_amdgcn_mfma_f32_16x16x32_bf16(va, pf, accO[c], 0, 0, 0);
    }
  }

  const float inv = 1.0f / l_run;
  const int token = q0 + wave * 16 + col;
  u16* orow = fused + (size_t)token * DMODEL + h * HDIM;
#pragma unroll
  for (int c = 0; c < 8; ++c) {
    u32 a = (u32)f2b(accO[c][0] * inv) | ((u32)f2b(accO[c][1] * inv) << 16);
    u32 b = (u32)f2b(accO[c][2] * inv) | ((u32)f2b(accO[c][3] * inv) << 16);
    *(u32*)(orow + c * 16 + quad * 4) = a;
    *(u32*)(orow + c * 16 + quad * 4 + 2) = b;
  }
}

extern "C" void kernel_launch(void* const* d_in, const int* in_sizes, int n_in,
                              void* d_out, int out_size, void* d_ws, size_t ws_size,
                              hipStream_t stream) {
  (void)in_sizes; (void)n_in; (void)out_size; (void)ws_size;
  const float* x   = (const float*)d_in[0];
  const float* fr  = (const float*)d_in[1];
  const float* qw  = (const float*)d_in[2];
  const float* qb  = (const float*)d_in[3];
  const float* kw  = (const float*)d_in[4];
  const float* kb  = (const float*)d_in[5];
  const float* vw  = (const float*)d_in[6];
  const float* vb  = (const float*)d_in[7];
  const float* ow  = (const float*)d_in[8];
  const float* ob  = (const float*)d_in[9];
  const float* nqw = (const float*)d_in[10];
  const float* nkw = (const float*)d_in[11];

  // bf16 intermediates: q(->fused) + v in ws (22 MB). d_out (fp32, 22 MB) is dead
  // until gemm_out: k borrows its lower 11 MB, vt (transposed V) the upper 11 MB.
  u16* qf = (u16*)d_ws;
  u16* vf = qf + (size_t)TS * DMODEL;
  u16* kf = (u16*)d_out;
  u16* vtb = (u16*)d_out + (size_t)TS * DMODEL;

  gemm_qkv<<<dim3(DMODEL / 128, TS / 128, 3), dim3(256), 0, stream>>>(
      x, qw, qb, kw, kb, vw, vb, qf, kf, vf);
  rmsnorm_rope<<<dim3(TS, 2), dim3(256), 0, stream>>>(qf, kf, fr, nqw, nkw);
  transpose_v<<<dim3(TS / 128, NHEAD), dim3(128), 0, stream>>>(vf, vtb);
  attn_mfma<<<dim3(TS / 64, NHEAD), dim3(256), 0, stream>>>(qf, kf, vtb, qf);
  gemm_out<<<dim3(DMODEL / 128, TS / 128), dim3(256), 0, stream>>>(
      qf, ow, ob, (float*)d_out);
}

// Round 7
// 401.691 us; speedup vs baseline: 18.6386x; 2.8464x over previous
//
#include <hip/hip_runtime.h>

#define TS 3584
#define VS 1792
#define TPF 448
#define NHEAD 12
#define HDIM 128
#define DMODEL 1536
#define ATTN_SCALE 0.08838834764831845f

typedef unsigned short u16;
typedef unsigned int u32;
typedef __attribute__((ext_vector_type(8))) short bf16x8;
typedef __attribute__((ext_vector_type(4))) float f32x4;

__device__ __forceinline__ float u2f(u32 u) { union { u32 u; float f; } c; c.u = u; return c.f; }
__device__ __forceinline__ float blo(u32 u) { return u2f(u << 16); }
__device__ __forceinline__ float bhi(u32 u) { return u2f(u & 0xffff0000u); }
__device__ __forceinline__ u16 f2b(float f) {
  union { float f; u32 u; } c; c.f = f;
  return (u16)((c.u + 0x7fffu + ((c.u >> 16) & 1u)) >> 16);
}

// Pack fp32 tensors to bf16 (RNE). z: 0=x, 1..3=q/k/v weights (concat), 4=o_w.
__global__ __launch_bounds__(256) void convert_bf16(
    const float* __restrict__ x, const float* __restrict__ qw,
    const float* __restrict__ kw, const float* __restrict__ vw,
    const float* __restrict__ ow, u16* __restrict__ xb,
    u16* __restrict__ wqkv, u16* __restrict__ owb) {
  const int z = blockIdx.y;
  const float* src;
  u16* dst;
  int n8;
  if (z == 0)      { src = x;  dst = xb;  n8 = TS * DMODEL / 8; }
  else if (z == 4) { src = ow; dst = owb; n8 = DMODEL * DMODEL / 8; }
  else {
    src = (z == 1) ? qw : (z == 2) ? kw : vw;
    dst = wqkv + (size_t)(z - 1) * DMODEL * DMODEL;
    n8 = DMODEL * DMODEL / 8;
  }
  const int idx = blockIdx.x * 256 + threadIdx.x;
  if (idx >= n8) return;
  const float4 a = ((const float4*)src)[2 * idx];
  const float4 b = ((const float4*)src)[2 * idx + 1];
  uint4 o;
  o.x = (u32)f2b(a.x) | ((u32)f2b(a.y) << 16);
  o.y = (u32)f2b(a.z) | ((u32)f2b(a.w) << 16);
  o.z = (u32)f2b(b.x) | ((u32)f2b(b.y) << 16);
  o.w = (u32)f2b(b.z) | ((u32)f2b(b.w) << 16);
  ((uint4*)dst)[idx] = o;
}

// MFMA NT GEMM: C[m,n] = sum_k A[m,k]*W[n,k] + bias[n]. A,W bf16 K-major, K=1536.
// 128x128 tile, BK=64, 256 thr = 4 waves, each wave 64x64 via 4x4 mfma 16x16x32.
// LDS XOR-swizzled (8-elem chunks) -> conflict-free ds_read_b128 / ds_write_b128.
// QKV=true: N=4608 (q|k|v sections, 128-aligned -> block-uniform), bf16 out + bias.
// QKV=false: fp32 out + bias (final projection into d_out).
template <bool QKV>
__global__ __launch_bounds__(256) void gemm_mfma(
    const u16* __restrict__ A, const u16* __restrict__ W,
    const float* __restrict__ b0, const float* __restrict__ b1,
    const float* __restrict__ b2,
    u16* __restrict__ o0, u16* __restrict__ o1, u16* __restrict__ o2,
    float* __restrict__ of) {
  __shared__ __align__(16) u16 Als[128 * 64];
  __shared__ __align__(16) u16 Bls[128 * 64];
  const int t = threadIdx.x;
  const int wave = t >> 6, lane = t & 63, col = lane & 15, quad = lane >> 4;
  const int m0 = blockIdx.y * 128, n0 = blockIdx.x * 128;
  const int wm = (wave & 1) * 64, wn = (wave >> 1) * 64;
  f32x4 acc[4][4];
#pragma unroll
  for (int i = 0; i < 4; ++i)
#pragma unroll
    for (int j = 0; j < 4; ++j) acc[i][j] = (f32x4){0.f, 0.f, 0.f, 0.f};

  for (int k0 = 0; k0 < DMODEL; k0 += 64) {
    __syncthreads();
#pragma unroll
    for (int i = 0; i < 4; ++i) {
      const int idx = t + i * 256;
      const int row = idx >> 3, ch = idx & 7;
      *(uint4*)&Als[row * 64 + ((ch ^ (row & 7)) * 8)] =
          *(const uint4*)(A + (size_t)(m0 + row) * DMODEL + k0 + ch * 8);
      *(uint4*)&Bls[row * 64 + ((ch ^ (row & 7)) * 8)] =
          *(const uint4*)(W + (size_t)(n0 + row) * DMODEL + k0 + ch * 8);
    }
    __syncthreads();
#pragma unroll
    for (int s = 0; s < 2; ++s) {
      bf16x8 af[4], bv[4];
#pragma unroll
      for (int i = 0; i < 4; ++i) {
        const int r = wm + i * 16 + col;
        af[i] = *(const bf16x8*)&Als[r * 64 + (((s * 4 + quad) ^ (r & 7)) * 8)];
      }
#pragma unroll
      for (int j = 0; j < 4; ++j) {
        const int r = wn + j * 16 + col;
        bv[j] = *(const bf16x8*)&Bls[r * 64 + (((s * 4 + quad) ^ (r & 7)) * 8)];
      }
#pragma unroll
      for (int i = 0; i < 4; ++i)
#pragma unroll
        for (int j = 0; j < 4; ++j)
          acc[i][j] = __builtin_amdgcn_mfma_f32_16x16x32_bf16(af[i], bv[j], acc[i][j], 0, 0, 0);
    }
  }

#pragma unroll
  for (int j = 0; j < 4; ++j) {
    const int ng = n0 + wn + j * 16 + col;
    if constexpr (QKV) {
      const int sec = ng / DMODEL;       // block-uniform
      const int nn = ng - sec * DMODEL;
      u16* dst = sec == 0 ? o0 : (sec == 1 ? o1 : o2);
      const float bias = sec == 0 ? b0[nn] : (sec == 1 ? b1[nn] : b2[nn]);
#pragma unroll
      for (int i = 0; i < 4; ++i) {
        const int mb = m0 + wm + i * 16 + quad * 4;
#pragma unroll
        for (int r = 0; r < 4; ++r)
          dst[(size_t)(mb + r) * DMODEL + nn] = f2b(acc[i][j][r] + bias);
      }
    } else {
      const float bias = b0[ng];
#pragma unroll
      for (int i = 0; i < 4; ++i) {
        const int mb = m0 + wm + i * 16 + quad * 4;
#pragma unroll
        for (int r = 0; r < 4; ++r)
          of[(size_t)(mb + r) * DMODEL + ng] = acc[i][j][r] + bias;
      }
    }
  }
}

// In-place RMSNorm(+weight) then RoPE on bf16 rows. blockIdx.x = token; y: 0=q,1=k.
__global__ __launch_bounds__(256) void rmsnorm_rope(
    u16* qbuf, u16* kbuf, const float* __restrict__ freqs,
    const float* __restrict__ nqw, const float* __restrict__ nkw) {
  const int tok = blockIdx.x;
  u32* row = (u32*)((blockIdx.y == 0 ? qbuf : kbuf) + (size_t)tok * DMODEL);
  const float* w = blockIdx.y == 0 ? nqw : nkw;
  const int t = threadIdx.x;
  const u32 u0 = row[t], u1 = row[t + 256], u2 = row[t + 512];
  float px[3] = { blo(u0), blo(u1), blo(u2) };
  float py[3] = { bhi(u0), bhi(u1), bhi(u2) };
  float ss = px[0] * px[0] + py[0] * py[0] + px[1] * px[1] + py[1] * py[1] +
             px[2] * px[2] + py[2] * py[2];
#pragma unroll
  for (int off = 32; off; off >>= 1) ss += __shfl_xor(ss, off);
  __shared__ float red[4];
  if ((t & 63) == 0) red[t >> 6] = ss;
  __syncthreads();
  const float rstd = rsqrtf((red[0] + red[1] + red[2] + red[3]) * (1.0f / DMODEL) + 1e-6f);
  const int p = tok % VS;
  const int fi = p / TPF, rem = p % TPF, hi = rem / 28, wi = rem % 28;
#pragma unroll
  for (int jj = 0; jj < 3; ++jj) {
    const int pj = t + jj * 256;
    const int i = pj & 63;
    const int prow = (i < 22) ? fi : ((i < 43) ? hi : wi);
    const float ang = freqs[prow * 64 + i];
    float sn, cs;
    sincosf(ang, &sn, &cs);
    const float a = px[jj] * rstd * w[2 * pj], b = py[jj] * rstd * w[2 * pj + 1];
    row[pj] = (u32)f2b(a * cs - b * sn) | ((u32)f2b(a * sn + b * cs) << 16);
  }
}

// vt[h][hd][tok] = v[tok][h*128+hd]. 128-thread blocks; in-register 8x8 u16 transpose.
__global__ __launch_bounds__(128) void transpose_v(
    const u16* __restrict__ v, u16* __restrict__ vt) {
  __shared__ __align__(16) u16 T[128 * 128];
  const int h = blockIdx.y;
  const int t0 = blockIdx.x * 128;
  const int t = threadIdx.x;
#pragma unroll
  for (int i = 0; i < 16; ++i) {
    int idx = t + i * 128;
    int tok = idx >> 4, hd8 = idx & 15;
    *(uint4*)&T[tok * 128 + ((hd8 ^ (tok & 7)) * 8)] =
        *(const uint4*)(v + (size_t)(t0 + tok) * DMODEL + h * HDIM + hd8 * 8);
  }
  __syncthreads();
  const int hb = t >> 3;                       // 16 hd-blocks
#pragma unroll
  for (int half = 0; half < 2; ++half) {
    const int tb = (t & 7) + half * 8;         // 16 tok-blocks
    uint4 M[8];
#pragma unroll
    for (int r = 0; r < 8; ++r)
      M[r] = *(const uint4*)&T[(tb * 8 + r) * 128 + ((hb ^ r) * 8)];
    uint4 O[8];
#pragma unroll
    for (int c2 = 0; c2 < 4; ++c2) {
      const u32* A = (const u32*)&M[2 * c2];
      const u32* Bp = (const u32*)&M[2 * c2 + 1];
#pragma unroll
      for (int jh = 0; jh < 4; ++jh) {
        u32 a = A[jh], b = Bp[jh];
        ((u32*)&O[2 * jh])[c2] = (a & 0xffffu) | (b << 16);
        ((u32*)&O[2 * jh + 1])[c2] = (a >> 16) | (b & 0xffff0000u);
      }
    }
#pragma unroll
    for (int j = 0; j < 8; ++j)
      *(uint4*)(vt + (size_t)(h * HDIM + hb * 8 + j) * TS + t0 + tb * 8) = O[j];
  }
}

// MFMA flash attention over union key set (in-view 1792 + cross-view same-frame 448).
__global__ __launch_bounds__(256) void attn_mfma(
    const u16* q, const u16* __restrict__ k,
    const u16* __restrict__ vt, u16* fused) {
  __shared__ __align__(16) u16 Kls[32 * 128];
  __shared__ __align__(16) u16 Vls[128 * 32];
  __shared__ __align__(16) u16 Qls[64 * 128];
  __shared__ __align__(16) u16 Pls[4][16 * 48];
  const int h = blockIdx.y;
  const int q0 = blockIdx.x * 64;
  const int t = threadIdx.x;
  const int wave = t >> 6;
  const int lane = t & 63;
  const int col = lane & 15, quad = lane >> 4;
  const int vview = q0 / VS;
  const int fidx = (q0 % VS) / TPF;

#pragma unroll
  for (int i = 0; i < 4; ++i) {
    int idx = t + i * 256;
    int qr = idx >> 4, hd8 = idx & 15;
    *(uint4*)&Qls[qr * 128 + ((hd8 ^ (qr & 7)) * 8)] =
        *(const uint4*)(q + (size_t)(q0 + qr) * DMODEL + h * HDIM + hd8 * 8);
  }
  __syncthreads();
  bf16x8 qfrag[4];
#pragma unroll
  for (int c = 0; c < 4; ++c)
    qfrag[c] = *(const bf16x8*)&Qls[(wave * 16 + col) * 128 +
                                    (((c * 4 + quad) ^ (col & 7)) * 8)];

  f32x4 accO[8];
#pragma unroll
  for (int c = 0; c < 8; ++c) accO[c] = (f32x4){0.f, 0.f, 0.f, 0.f};
  float m_run = -1e30f, l_run = 0.f;

  const int base0 = vview * VS;
  const int base1 = (1 - vview) * VS + fidx * TPF;

  for (int it = 0; it < 70; ++it) {
    const int base = (it < 56) ? (base0 + it * 32) : (base1 + (it - 56) * 32);
    __syncthreads();
#pragma unroll
    for (int i = 0; i < 2; ++i) {
      int idx = t + i * 256;
      int key = idx >> 4, hd8 = idx & 15;
      *(uint4*)&Kls[key * 128 + ((hd8 ^ (key & 7)) * 8)] =
          *(const uint4*)(k + (size_t)(base + key) * DMODEL + h * HDIM + hd8 * 8);
      int hd = idx >> 2, t8 = idx & 3;
      *(uint4*)&Vls[hd * 32 + ((t8 ^ (hd & 3)) * 8)] =
          *(const uint4*)(vt + (size_t)(h * HDIM + hd) * TS + base + t8 * 8);
    }
    __syncthreads();

    f32x4 s0 = (f32x4){0.f, 0.f, 0.f, 0.f}, s1 = (f32x4){0.f, 0.f, 0.f, 0.f};
#pragma unroll
    for (int c = 0; c < 4; ++c) {
      const int chn = ((c * 4 + quad) ^ (col & 7)) * 8;
      bf16x8 ka0 = *(const bf16x8*)&Kls[col * 128 + chn];
      bf16x8 ka1 = *(const bf16x8*)&Kls[(16 + col) * 128 + chn];
      s0 = __builtin_amdgcn_mfma_f32_16x16x32_bf16(ka0, qfrag[c], s0, 0, 0, 0);
      s1 = __builtin_amdgcn_mfma_f32_16x16x32_bf16(ka1, qfrag[c], s1, 0, 0, 0);
    }

    float lmax = -1e30f;
#pragma unroll
    for (int r = 0; r < 4; ++r) {
      s0[r] *= ATTN_SCALE; s1[r] *= ATTN_SCALE;
      lmax = fmaxf(lmax, fmaxf(s0[r], s1[r]));
    }
    lmax = fmaxf(lmax, __shfl_xor(lmax, 16));
    lmax = fmaxf(lmax, __shfl_xor(lmax, 32));
    const float mnew = fmaxf(m_run, lmax);
    const float alpha = __expf(m_run - mnew);
    float p0[4], p1[4], ps = 0.f;
#pragma unroll
    for (int r = 0; r < 4; ++r) {
      p0[r] = __expf(s0[r] - mnew);
      p1[r] = __expf(s1[r] - mnew);
      ps += p0[r] + p1[r];
    }
    ps += __shfl_xor(ps, 16);
    ps += __shfl_xor(ps, 32);
    l_run = l_run * alpha + ps;
    m_run = mnew;
#pragma unroll
    for (int c = 0; c < 8; ++c) {
      accO[c][0] *= alpha; accO[c][1] *= alpha;
      accO[c][2] *= alpha; accO[c][3] *= alpha;
    }

    uint2 w0, w1;
    w0.x = (u32)f2b(p0[0]) | ((u32)f2b(p0[1]) << 16);
    w0.y = (u32)f2b(p0[2]) | ((u32)f2b(p0[3]) << 16);
    w1.x = (u32)f2b(p1[0]) | ((u32)f2b(p1[1]) << 16);
    w1.y = (u32)f2b(p1[2]) | ((u32)f2b(p1[3]) << 16);
    *(uint2*)&Pls[wave][col * 48 + quad * 4] = w0;
    *(uint2*)&Pls[wave][col * 48 + 16 + quad * 4] = w1;
    asm volatile("s_waitcnt lgkmcnt(0)" ::: "memory");
    bf16x8 pf = *(const bf16x8*)&Pls[wave][col * 48 + quad * 8];

#pragma unroll
    for (int c = 0; c < 8; ++c) {
      bf16x8 va = *(const bf16x8*)&Vls[(c * 16 + col) * 32 + ((quad ^ (col & 3)) * 8)];
      accO[c] = __builtin_amdgcn_mfma_f32_16x16x32_bf16(va, pf, accO[c], 0, 0, 0);
    }
  }

  const float inv = 1.0f / l_run;
  const int token = q0 + wave * 16 + col;
  u16* orow = fused + (size_t)token * DMODEL + h * HDIM;
#pragma unroll
  for (int c = 0; c < 8; ++c) {
    u32 a = (u32)f2b(accO[c][0] * inv) | ((u32)f2b(accO[c][1] * inv) << 16);
    u32 b = (u32)f2b(accO[c][2] * inv) | ((u32)f2b(accO[c][3] * inv) << 16);
    *(u32*)(orow + c * 16 + quad * 4) = a;
    *(u32*)(orow + c * 16 + quad * 4 + 2) = b;
  }
}

extern "C" void kernel_launch(void* const* d_in, const int* in_sizes, int n_in,
                              void* d_out, int out_size, void* d_ws, size_t ws_size,
                              hipStream_t stream) {
  (void)in_sizes; (void)n_in; (void)out_size; (void)ws_size;
  const float* x   = (const float*)d_in[0];
  const float* fr  = (const float*)d_in[1];
  const float* qw  = (const float*)d_in[2];
  const float* qb  = (const float*)d_in[3];
  const float* kw  = (const float*)d_in[4];
  const float* kb  = (const float*)d_in[5];
  const float* vw  = (const float*)d_in[6];
  const float* vb  = (const float*)d_in[7];
  const float* ow  = (const float*)d_in[8];
  const float* ob  = (const float*)d_in[9];
  const float* nqw = (const float*)d_in[10];
  const float* nkw = (const float*)d_in[11];

  // ws (bf16 elems): qf(->fused) | vf | xb | wqkv(3x1536x1536) | owb  = ~52 MB.
  // d_out (fp32, 22 MB) dead until gemm_out: kf lower 11 MB, vtb upper 11 MB.
  u16* qf   = (u16*)d_ws;
  u16* vf   = qf + (size_t)TS * DMODEL;
  u16* xb   = vf + (size_t)TS * DMODEL;
  u16* wqkv = xb + (size_t)TS * DMODEL;
  u16* owb  = wqkv + (size_t)3 * DMODEL * DMODEL;
  u16* kf   = (u16*)d_out;
  u16* vtb  = (u16*)d_out + (size_t)TS * DMODEL;

  convert_bf16<<<dim3(TS * DMODEL / 8 / 256, 5), dim3(256), 0, stream>>>(
      x, qw, kw, vw, ow, xb, wqkv, owb);
  gemm_mfma<true><<<dim3(3 * DMODEL / 128, TS / 128), dim3(256), 0, stream>>>(
      xb, wqkv, qb, kb, vb, qf, kf, vf, nullptr);
  rmsnorm_rope<<<dim3(TS, 2), dim3(256), 0, stream>>>(qf, kf, fr, nqw, nkw);
  transpose_v<<<dim3(TS / 128, NHEAD), dim3(128), 0, stream>>>(vf, vtb);
  attn_mfma<<<dim3(TS / 64, NHEAD), dim3(256), 0, stream>>>(qf, kf, vtb, qf);
  gemm_mfma<false><<<dim3(DMODEL / 128, TS / 128), dim3(256), 0, stream>>>(
      qf, owb, ob, nullptr, nullptr, nullptr, nullptr, nullptr, (float*)d_out);
}